// Round 14
// baseline (228.077 us; speedup 1.0000x reference)
//
#include <hip/hip_runtime.h>
#include <math.h>

#define B_ 128
#define A_ 8732
#define C_ 21
#define APB 256                       // anchors per block (k_ce)
#define NBLK ((A_ + APB - 1) / APB)   // 35 blocks per row
#define TPB 1024                      // k_sel threads
#define KPT 9                         // ceil(A_/TPB) keys per thread

typedef float f4 __attribute__((ext_vector_type(4)));

// ws layout (bytes):
#define OFF_SCAL 0                    // {float gsum; int gN; int gticket}
#define OFF_RNP  16                   // int row_np[128]
#define OFF_CEN  1024                 // float ce_neg[128*8732]

// Online-softmax over 4 scalars; also grabs v[L] via select chain (rule #20:
// no dynamically-indexed register arrays).
#define SM4(e0, e1, e2, e3, BASE)                                     \
    {                                                                 \
        const float cm = fmaxf(fmaxf(e0, e1), fmaxf(e2, e3));         \
        const float nm = fmaxf(m, cm);                                \
        s = s * __expf(m - nm)                                        \
          + __expf(e0 - nm) + __expf(e1 - nm)                         \
          + __expf(e2 - nm) + __expf(e3 - nm);                        \
        m = nm;                                                       \
        vL = (L == (BASE) + 0) ? e0 : vL;                             \
        vL = (L == (BASE) + 1) ? e1 : vL;                             \
        vL = (L == (BASE) + 2) ? e2 : vL;                             \
        vL = (L == (BASE) + 3) ? e3 : vL;                             \
    }

// CE kernel, round-1 proven structure: COALESCED float4 staging of the conf
// tile into LDS (lane i -> consecutive 16B), then per-thread softmax from LDS.
// Rounds 7/9/12 all died on the same thing: anchor-per-thread global loads at
// stride 84B scatter each wave-instruction over ~84 cache lines -> VMEM issue
// bottleneck (787 GB/s, VALUBusy 11%). Staging restores 1KB/instr coalescing.
__global__ __launch_bounds__(256) void k_ce(
        const float* __restrict__ conf, const float* __restrict__ loc,
        const int* __restrict__ lab, const float* __restrict__ gloc,
        float* __restrict__ ce_neg, int* __restrict__ row_np,
        float* __restrict__ gsum)
{
    __shared__ float sConf[APB * C_];   // 21504 B
    const int row = blockIdx.y;
    const int a0  = blockIdx.x * APB;
    const int n   = min(APB, A_ - a0);
    const int tid = threadIdx.x;
    const int wave = tid >> 6, lane = tid & 63;

    // prefetch label early (independent of staging)
    const int aa = a0 + min(tid, n - 1);
    const int L  = lab[(size_t)row * A_ + aa];

    // stage conf tile: consecutive lanes read consecutive float4 (coalesced).
    // Alignment: (row*A_ + a0)*C_*4B is 16B-aligned for all blocks
    // (733488 and 21504 both divisible by 16).
    {
        const size_t base = ((size_t)row * A_ + a0) * C_;
        const int n4 = (n * C_) >> 2;          // n*21 divisible by 4 (n=256|28)
        const f4* src4 = (const f4*)(conf + base);
        f4* dst4 = (f4*)sConf;
        #pragma unroll
        for (int j = 0; j < 6; ++j) {
            const int i = tid + j * 256;
            if (i < n4) dst4[i] = src4[i];
        }
    }
    __syncthreads();

    float pce = 0.f, lloss = 0.f;
    int pcnt = 0;

    if (tid < n) {
        const size_t idx = (size_t)row * A_ + a0 + tid;
        const float* vp = sConf + tid * C_;    // LDS: bank 2-way max (gcd(21,32)=1)

        float m = -1e30f, s = 0.f, vL = 0.f;
        SM4(vp[0],  vp[1],  vp[2],  vp[3],   0)
        SM4(vp[4],  vp[5],  vp[6],  vp[7],   4)
        SM4(vp[8],  vp[9],  vp[10], vp[11],  8)
        SM4(vp[12], vp[13], vp[14], vp[15], 12)
        SM4(vp[16], vp[17], vp[18], vp[19], 16)
        {   // scalar element 20
            const float e = vp[20];
            const float nm = fmaxf(m, e);
            s = s * __expf(m - nm) + __expf(e - nm);
            m = nm;
            vL = (L == 20) ? e : vL;
        }
        const float ce = __logf(s) + m - vL;

        if (L > 0) {
            pce = ce;
            pcnt = 1;
            const float4 lv = ((const float4*)loc)[idx];
            const float4 gv = ((const float4*)gloc)[idx];
            float dx = lv.x - gv.x, dy = lv.y - gv.y,
                  dz = lv.z - gv.z, dw = lv.w - gv.w;
            float ax = fabsf(dx), ay = fabsf(dy),
                  az = fabsf(dz), aw = fabsf(dw);
            lloss  = (ax < 1.f) ? 0.5f * dx * dx : ax - 0.5f;
            lloss += (ay < 1.f) ? 0.5f * dy * dy : ay - 0.5f;
            lloss += (az < 1.f) ? 0.5f * dz * dz : az - 0.5f;
            lloss += (aw < 1.f) ? 0.5f * dw * dw : aw - 0.5f;
            ce_neg[idx] = 0.f;              // positives excluded from mining
        } else {
            ce_neg[idx] = ce;               // CE >= 0
        }
    }

    // block reduce -> device atomics (4480 blocks x 2 atomics: negligible)
    #pragma unroll
    for (int off = 32; off > 0; off >>= 1) {
        pce   += __shfl_down(pce, off);
        lloss += __shfl_down(lloss, off);
        pcnt  += __shfl_down(pcnt, off);
    }
    __shared__ float wf[4], wl[4];
    __shared__ int wc[4];
    if (lane == 0) { wf[wave] = pce; wl[wave] = lloss; wc[wave] = pcnt; }
    __syncthreads();
    if (tid == 0) {
        const float S = wf[0] + wf[1] + wf[2] + wf[3]
                      + wl[0] + wl[1] + wl[2] + wl[3];
        const int Cc = wc[0] + wc[1] + wc[2] + wc[3];
        if (S != 0.f) atomicAdd(gsum, S);
        if (Cc)       atomicAdd(&row_np[row], Cc);
    }
}

// Per-row exact top-k sum via quaternary ballot search. Keys live in LDS
// (36 KB), NOT registers — per-thread keys[9] register arrays spilled at
// 1024 threads (rounds 7/9). Staging reads ce[tid + j*1024]: consecutive
// lanes -> consecutive 4B, coalesced. LDS pattern kls[tid + j*1024] is
// 2 lanes/bank: free.
__global__ __launch_bounds__(1024) void k_sel(
        const float* __restrict__ ce_neg, const int* __restrict__ row_np,
        float* __restrict__ gsum, int* __restrict__ gN,
        int* __restrict__ gticket, float* __restrict__ out)
{
    __shared__ unsigned kls[KPT * TPB];        // 9216 slots >= A_, 36 KB
    __shared__ unsigned long long shCnt[2][16];
    __shared__ float shS[16];

    const int b = blockIdx.x;
    const int tid = threadIdx.x;
    const int wave = tid >> 6, lane = tid & 63;
    const float* ce = ce_neg + (size_t)b * A_;

    // stage row keys into LDS (bit patterns; CE >= 0 so uint order == float)
    #pragma unroll
    for (int j = 0; j < KPT; ++j) {
        const int i = tid + j * TPB;
        kls[i] = (i < A_) ? __float_as_uint(ce[i]) : 0u;
    }
    const int np = row_np[b];
    if (tid == 0) atomicAdd(gN, np);
    __syncthreads();

    // zero-pass: count & sum of strictly-positive keys
    {
        unsigned c0 = 0; float s0 = 0.f;
        #pragma unroll
        for (int j = 0; j < KPT; ++j) {
            const unsigned key = kls[tid + j * TPB];
            c0 += (unsigned)__popcll(__ballot(key != 0u));
            s0 += __uint_as_float(key);          // +0.0f when key==0
        }
        #pragma unroll
        for (int off = 32; off > 0; off >>= 1) s0 += __shfl_down(s0, off);
        if (lane == 0) { shCnt[0][wave] = c0; shS[wave] = s0; }
    }
    __syncthreads();

    const int k = min(3 * np, A_ - np);
    unsigned cnt0 = 0; float sum0 = 0.f;
    #pragma unroll
    for (int w = 0; w < 16; ++w) { cnt0 += (unsigned)shCnt[0][w]; sum0 += shS[w]; }

    float negsum = 0.f;          // valid at tid==0
    if (k <= 0) {
        negsum = 0.f;
    } else if (cnt0 < (unsigned)k) {
        negsum = sum0;
    } else {
        unsigned lo = 0u, hi = 0x42800000u;   // CE < 64.0 certain for this data
        int p = 1;
        while (hi - lo > 1u) {
            const unsigned w = hi - lo;
            unsigned m1, m2, m3;
            if (w >= 4u) { const unsigned q = w >> 2; m1 = lo + q; m2 = lo + 2*q; m3 = lo + 3*q; }
            else         { m1 = m2 = m3 = lo + (w >> 1); }
            unsigned c1 = 0, c2 = 0, c3 = 0;
            #pragma unroll
            for (int j = 0; j < KPT; ++j) {
                const unsigned key = kls[tid + j * TPB];
                c1 += (unsigned)__popcll(__ballot(key > m1));
                c2 += (unsigned)__popcll(__ballot(key > m2));
                c3 += (unsigned)__popcll(__ballot(key > m3));
            }
            if (lane == 0)
                shCnt[p][wave] = (unsigned long long)c1
                               | ((unsigned long long)c2 << 16)
                               | ((unsigned long long)c3 << 32);
            __syncthreads();
            unsigned long long tsum = 0;
            #pragma unroll
            for (int w2 = 0; w2 < 16; ++w2) tsum += shCnt[p][w2];
            const int C1 = (int)(tsum & 0xFFFF), C2 = (int)((tsum >> 16) & 0xFFFF),
                      C3 = (int)((tsum >> 32) & 0xFFFF);
            if      (C3 >= k) { lo = m3; }
            else if (C2 >= k) { lo = m2; hi = m3; }
            else if (C1 >= k) { lo = m1; hi = m2; }
            else              { hi = m1; }
            p ^= 1;
        }

        // kth-largest bit pattern == hi (invariant: count(>lo) >= k > count(>hi))
        const unsigned kth = hi;
        unsigned c = 0; float s = 0.f;
        #pragma unroll
        for (int j = 0; j < KPT; ++j) {
            const unsigned key = kls[tid + j * TPB];
            c += (unsigned)__popcll(__ballot(key > kth));
            s += (key > kth) ? __uint_as_float(key) : 0.f;
        }
        #pragma unroll
        for (int off = 32; off > 0; off >>= 1) s += __shfl_down(s, off);
        if (lane == 0) { shCnt[0][wave] = c; shS[wave] = s; }
        __syncthreads();
        if (tid == 0) {
            unsigned Cg = 0; float Sg = 0.f;
            #pragma unroll
            for (int w = 0; w < 16; ++w) { Cg += (unsigned)shCnt[0][w]; Sg += shS[w]; }
            negsum = Sg + (float)(k - (int)Cg) * __uint_as_float(kth);
        }
    }

    // epilogue: contribute, ticket, last of the 128 blocks finalizes
    if (tid == 0) {
        atomicAdd(gsum, negsum);
        __threadfence();
        const int t = atomicAdd(gticket, 1);
        if (t == B_ - 1) {
            const float S = atomicAdd(gsum, 0.f);   // coherent read-back
            const int   N = atomicAdd(gN, 0);
            out[0] = S / (float)N;
        }
    }
}

extern "C" void kernel_launch(void* const* d_in, const int* in_sizes, int n_in,
                              void* d_out, int out_size, void* d_ws, size_t ws_size,
                              hipStream_t stream) {
    const float* conf = (const float*)d_in[0];   // (B, A, C) f32
    const float* loc  = (const float*)d_in[1];   // (B, A, 4) f32
    const int*   lab  = (const int*)d_in[2];     // (B, A) i32
    const float* gloc = (const float*)d_in[3];   // (B, A, 4) f32

    char* ws = (char*)d_ws;
    float* gsum   = (float*)(ws + OFF_SCAL);
    int*   gN     = (int*)(ws + OFF_SCAL + 4);
    int*   gticket= (int*)(ws + OFF_SCAL + 8);
    int*   row_np = (int*)(ws + OFF_RNP);
    float* ce_neg = (float*)(ws + OFF_CEN);

    // zero scalars + row_np (528 B; capture-legal stream-ordered fill)
    hipMemsetAsync(ws, 0, OFF_RNP + B_ * sizeof(int), stream);

    dim3 g1(NBLK, B_);
    k_ce<<<g1, APB, 0, stream>>>(conf, loc, lab, gloc, ce_neg, row_np, gsum);
    k_sel<<<B_, TPB, 0, stream>>>(ce_neg, row_np, gsum, gN, gticket,
                                  (float*)d_out);
}

// Round 23
// 193.735 us; speedup vs baseline: 1.1773x; 1.1773x over previous
//
#include <hip/hip_runtime.h>
#include <math.h>

#define B_ 128
#define A_ 8732
#define C_ 21
#define APB 256                       // anchors per block (k_ce)
#define NBLK 35                       // ceil(8732/256)
#define NPART (B_ * NBLK)             // 4480 partials
#define TPB 1024                      // k_sel threads
#define KPT 9                         // ceil(A_/TPB) keys per thread

typedef float f4 __attribute__((ext_vector_type(4)));

// ws layout (bytes):
#define OFF_SCAL 0                    // {float gsum; int gN; int gticket}
#define OFF_PALL 1024                 // float part_all[4480] (pce+lloss per block)
#define OFF_PNP  18944                // int   part_np[4480]
#define OFF_CEN  36864                // float ce_neg[128*8732]

// Online-softmax over 4 scalars; also grabs v[L] via select chain (rule #20:
// no dynamically-indexed register arrays).
#define SM4(e0, e1, e2, e3, BASE)                                     \
    {                                                                 \
        const float cm = fmaxf(fmaxf(e0, e1), fmaxf(e2, e3));         \
        const float nm = fmaxf(m, cm);                                \
        s = s * __expf(m - nm)                                        \
          + __expf(e0 - nm) + __expf(e1 - nm)                         \
          + __expf(e2 - nm) + __expf(e3 - nm);                        \
        m = nm;                                                       \
        vL = (L == (BASE) + 0) ? e0 : vL;                             \
        vL = (L == (BASE) + 1) ? e1 : vL;                             \
        vL = (L == (BASE) + 2) ? e2 : vL;                             \
        vL = (L == (BASE) + 3) ? e3 : vL;                             \
    }

// CE kernel — round-1 structure restored EXACTLY on the output side:
// plain per-block partial stores, ZERO atomics. Rounds 12/14 added 4480
// same-address atomicAdds to gsum and both landed at 74-80us with VALU and
// HBM simultaneously idle (11%/9%) — same-address device atomics serialize
// at ~15-20ns each ≈ 70-90us, matching. Round-1's atomic-free k_ce was <55us.
__global__ __launch_bounds__(256) void k_ce(
        const float* __restrict__ conf, const float* __restrict__ loc,
        const int* __restrict__ lab, const float* __restrict__ gloc,
        float* __restrict__ ce_neg, float* __restrict__ part_all,
        int* __restrict__ part_np)
{
    __shared__ float sConf[APB * C_];   // 21504 B
    const int row = blockIdx.y;
    const int a0  = blockIdx.x * APB;
    const int n   = min(APB, A_ - a0);
    const int tid = threadIdx.x;
    const int wave = tid >> 6, lane = tid & 63;

    // prefetch label early (independent of staging)
    const int aa = a0 + min(tid, n - 1);
    const int L  = lab[(size_t)row * A_ + aa];

    // stage conf tile: consecutive lanes read consecutive float4 (coalesced).
    // Alignment: (row*A_+a0)*C_*4B is 16B-aligned (733488, 21504 both /16).
    {
        const size_t base = ((size_t)row * A_ + a0) * C_;
        const int n4 = (n * C_) >> 2;          // n*21 divisible by 4 (n=256|28)
        const f4* src4 = (const f4*)(conf + base);
        f4* dst4 = (f4*)sConf;
        #pragma unroll
        for (int j = 0; j < 6; ++j) {
            const int i = tid + j * 256;
            if (i < n4) dst4[i] = src4[i];
        }
    }
    __syncthreads();

    float pce = 0.f, lloss = 0.f;
    int pcnt = 0;

    if (tid < n) {
        const size_t idx = (size_t)row * A_ + a0 + tid;
        const float* vp = sConf + tid * C_;    // LDS: <=2 lanes/bank (gcd(21,32)=1)

        float m = -1e30f, s = 0.f, vL = 0.f;
        SM4(vp[0],  vp[1],  vp[2],  vp[3],   0)
        SM4(vp[4],  vp[5],  vp[6],  vp[7],   4)
        SM4(vp[8],  vp[9],  vp[10], vp[11],  8)
        SM4(vp[12], vp[13], vp[14], vp[15], 12)
        SM4(vp[16], vp[17], vp[18], vp[19], 16)
        {   // scalar element 20
            const float e = vp[20];
            const float nm = fmaxf(m, e);
            s = s * __expf(m - nm) + __expf(e - nm);
            m = nm;
            vL = (L == 20) ? e : vL;
        }
        const float ce = __logf(s) + m - vL;

        if (L > 0) {
            pce = ce;
            pcnt = 1;
            const float4 lv = ((const float4*)loc)[idx];
            const float4 gv = ((const float4*)gloc)[idx];
            float dx = lv.x - gv.x, dy = lv.y - gv.y,
                  dz = lv.z - gv.z, dw = lv.w - gv.w;
            float ax = fabsf(dx), ay = fabsf(dy),
                  az = fabsf(dz), aw = fabsf(dw);
            lloss  = (ax < 1.f) ? 0.5f * dx * dx : ax - 0.5f;
            lloss += (ay < 1.f) ? 0.5f * dy * dy : ay - 0.5f;
            lloss += (az < 1.f) ? 0.5f * dz * dz : az - 0.5f;
            lloss += (aw < 1.f) ? 0.5f * dw * dw : aw - 0.5f;
            ce_neg[idx] = 0.f;              // positives excluded from mining
        } else {
            ce_neg[idx] = ce;               // CE >= 0
        }
    }

    // block reduce -> PLAIN partial stores (no atomics)
    #pragma unroll
    for (int off = 32; off > 0; off >>= 1) {
        pce   += __shfl_down(pce, off);
        lloss += __shfl_down(lloss, off);
        pcnt  += __shfl_down(pcnt, off);
    }
    __shared__ float wf[4], wl[4];
    __shared__ int wc[4];
    if (lane == 0) { wf[wave] = pce; wl[wave] = lloss; wc[wave] = pcnt; }
    __syncthreads();
    if (tid == 0) {
        const int bid = row * NBLK + blockIdx.x;
        part_all[bid] = wf[0] + wf[1] + wf[2] + wf[3]
                      + wl[0] + wl[1] + wl[2] + wl[3];
        part_np[bid]  = wc[0] + wc[1] + wc[2] + wc[3];
    }
}

// Per-row exact top-k sum via quaternary ballot search. Keys in LDS (36 KB,
// spill-proof; per-thread keys[9] register arrays spilled in rounds 7/9).
// Wave 0 additionally reduces the row's 35 loc/CE/np partials (round-1's
// proven lane<35 pattern). ONE gsum atomic + one gN atomic per block
// (384 same-address atomics total, vs 8960 in rounds 12/14).
__global__ __launch_bounds__(1024) void k_sel(
        const float* __restrict__ ce_neg, const float* __restrict__ part_all,
        const int* __restrict__ part_np, float* __restrict__ gsum,
        int* __restrict__ gN, int* __restrict__ gticket,
        float* __restrict__ out)
{
    __shared__ unsigned kls[KPT * TPB];        // 9216 slots >= A_, 36 KB
    __shared__ unsigned long long shCnt[2][16];
    __shared__ float shS[16];
    __shared__ int shNp;

    const int b = blockIdx.x;
    const int tid = threadIdx.x;
    const int wave = tid >> 6, lane = tid & 63;
    const float* ce = ce_neg + (size_t)b * A_;

    // stage row keys into LDS (bit patterns; CE >= 0 so uint order == float)
    #pragma unroll
    for (int j = 0; j < KPT; ++j) {
        const int i = tid + j * TPB;
        kls[i] = (i < A_) ? __float_as_uint(ce[i]) : 0u;
    }

    // wave 0: reduce this row's 35 partials (np + loc/posCE sum)
    float rowpart = 0.f;                       // valid at tid==0 after reduce
    if (wave == 0) {
        int v = (lane < NBLK) ? part_np[b * NBLK + lane] : 0;
        float pa = (lane < NBLK) ? part_all[b * NBLK + lane] : 0.f;
        #pragma unroll
        for (int off = 32; off > 0; off >>= 1) {
            v  += __shfl_down(v, off);
            pa += __shfl_down(pa, off);
        }
        if (lane == 0) { shNp = v; rowpart = pa; }
    }
    __syncthreads();
    const int np = shNp;

    // zero-pass: count & sum of strictly-positive keys
    {
        unsigned c0 = 0; float s0 = 0.f;
        #pragma unroll
        for (int j = 0; j < KPT; ++j) {
            const unsigned key = kls[tid + j * TPB];
            c0 += (unsigned)__popcll(__ballot(key != 0u));
            s0 += __uint_as_float(key);          // +0.0f when key==0
        }
        #pragma unroll
        for (int off = 32; off > 0; off >>= 1) s0 += __shfl_down(s0, off);
        if (lane == 0) { shCnt[0][wave] = c0; shS[wave] = s0; }
    }
    __syncthreads();

    const int k = min(3 * np, A_ - np);
    unsigned cnt0 = 0; float sum0 = 0.f;
    #pragma unroll
    for (int w = 0; w < 16; ++w) { cnt0 += (unsigned)shCnt[0][w]; sum0 += shS[w]; }

    float negsum = 0.f;          // valid at tid==0
    if (k <= 0) {
        negsum = 0.f;
    } else if (cnt0 < (unsigned)k) {
        negsum = sum0;
    } else {
        unsigned lo = 0u, hi = 0x42800000u;   // CE < 64.0 certain for this data
        int p = 1;
        while (hi - lo > 1u) {
            const unsigned w = hi - lo;
            unsigned m1, m2, m3;
            if (w >= 4u) { const unsigned q = w >> 2; m1 = lo + q; m2 = lo + 2*q; m3 = lo + 3*q; }
            else         { m1 = m2 = m3 = lo + (w >> 1); }
            unsigned c1 = 0, c2 = 0, c3 = 0;
            #pragma unroll
            for (int j = 0; j < KPT; ++j) {
                const unsigned key = kls[tid + j * TPB];
                c1 += (unsigned)__popcll(__ballot(key > m1));
                c2 += (unsigned)__popcll(__ballot(key > m2));
                c3 += (unsigned)__popcll(__ballot(key > m3));
            }
            if (lane == 0)
                shCnt[p][wave] = (unsigned long long)c1
                               | ((unsigned long long)c2 << 16)
                               | ((unsigned long long)c3 << 32);
            __syncthreads();
            unsigned long long tsum = 0;
            #pragma unroll
            for (int w2 = 0; w2 < 16; ++w2) tsum += shCnt[p][w2];
            const int C1 = (int)(tsum & 0xFFFF), C2 = (int)((tsum >> 16) & 0xFFFF),
                      C3 = (int)((tsum >> 32) & 0xFFFF);
            if      (C3 >= k) { lo = m3; }
            else if (C2 >= k) { lo = m2; hi = m3; }
            else if (C1 >= k) { lo = m1; hi = m2; }
            else              { hi = m1; }
            p ^= 1;
        }

        // kth-largest bit pattern == hi (invariant: count(>lo) >= k > count(>hi))
        const unsigned kth = hi;
        unsigned c = 0; float s = 0.f;
        #pragma unroll
        for (int j = 0; j < KPT; ++j) {
            const unsigned key = kls[tid + j * TPB];
            c += (unsigned)__popcll(__ballot(key > kth));
            s += (key > kth) ? __uint_as_float(key) : 0.f;
        }
        #pragma unroll
        for (int off = 32; off > 0; off >>= 1) s += __shfl_down(s, off);
        if (lane == 0) { shCnt[0][wave] = c; shS[wave] = s; }
        __syncthreads();
        if (tid == 0) {
            unsigned Cg = 0; float Sg = 0.f;
            #pragma unroll
            for (int w = 0; w < 16; ++w) { Cg += (unsigned)shCnt[0][w]; Sg += shS[w]; }
            negsum = Sg + (float)(k - (int)Cg) * __uint_as_float(kth);
        }
    }

    // epilogue: contribute (row partials + mined negatives), ticket, finalize
    if (tid == 0) {
        atomicAdd(gsum, rowpart + negsum);
        atomicAdd(gN, np);
        __threadfence();
        const int t = atomicAdd(gticket, 1);
        if (t == B_ - 1) {
            const float S = atomicAdd(gsum, 0.f);   // coherent read-back
            const int   N = atomicAdd(gN, 0);
            out[0] = S / (float)N;
        }
    }
}

extern "C" void kernel_launch(void* const* d_in, const int* in_sizes, int n_in,
                              void* d_out, int out_size, void* d_ws, size_t ws_size,
                              hipStream_t stream) {
    const float* conf = (const float*)d_in[0];   // (B, A, C) f32
    const float* loc  = (const float*)d_in[1];   // (B, A, 4) f32
    const int*   lab  = (const int*)d_in[2];     // (B, A) i32
    const float* gloc = (const float*)d_in[3];   // (B, A, 4) f32

    char* ws = (char*)d_ws;
    float* gsum     = (float*)(ws + OFF_SCAL);
    int*   gN       = (int*)(ws + OFF_SCAL + 4);
    int*   gticket  = (int*)(ws + OFF_SCAL + 8);
    float* part_all = (float*)(ws + OFF_PALL);
    int*   part_np  = (int*)(ws + OFF_PNP);
    float* ce_neg   = (float*)(ws + OFF_CEN);

    // zero the cross-kernel scalars only (12 B; partials fully overwritten)
    hipMemsetAsync(ws, 0, 12, stream);

    dim3 g1(NBLK, B_);
    k_ce<<<g1, APB, 0, stream>>>(conf, loc, lab, gloc, ce_neg,
                                 part_all, part_np);
    k_sel<<<B_, TPB, 0, stream>>>(ce_neg, part_all, part_np,
                                  gsum, gN, gticket, (float*)d_out);
}